// Round 3
// baseline (24970.334 us; speedup 1.0000x reference)
//
#include <hip/hip_runtime.h>
#include <math.h>

#define NB 1024      // batch
#define NH 256       // hidden
#define NLOOK 336    // encoder steps
#define NHOR 168     // decoder steps
#define TPB 256

// Block tiling per launch: grid=256 = 16 batch-tiles (64 rows) x 16 hidden-tiles (16 h cols).
// Thread: r = tx&15 owns batch rows 4r..4r+3 ; c = tx>>4 owns h-column hg = htile*16+c (all 4 gates).
// GEMM K=256 staged in two 128-wide chunks; As+Bs = 64 KiB LDS.

__device__ __forceinline__ float sigm(float x) { return 1.0f / (1.0f + expf(-x)); }

// Stage 64x128 fp32 chunk of h into LDS; slot (R,q) holds src float4 q ^ ((R>>2)&7).
__device__ __forceinline__ void stage_h_chunk(float4* dst, const float* __restrict__ src,
                                              int b0, int kc, int tx) {
#pragma unroll
  for (int i = 0; i < 8; ++i) {
    const int flat = i * 256 + tx;
    const int R = flat >> 5, q = flat & 31;
    const float4 v = ((const float4*)(src + (b0 + R) * NH + kc * 128))[q];
    dst[R * 32 + (q ^ ((R >> 2) & 7))] = v;
  }
}

// Stage 64x128 chunk of W rows (gate-major): LDS row R = g*16+hl <- W[g*256+h0+hl][kc*128..].
__device__ __forceinline__ void stage_w_chunk(float4* dst, const float* __restrict__ W,
                                              int h0, int kc, int tx) {
#pragma unroll
  for (int i = 0; i < 8; ++i) {
    const int flat = i * 256 + tx;
    const int R = flat >> 5, q = flat & 31;
    const int g = R >> 4, hl = R & 15;
    const float4 v = ((const float4*)(W + (g * NH + h0 + hl) * NH + kc * 128))[q];
    dst[R * 32 + (q ^ (R & 7))] = v;
  }
}

// acc[i][g] += sum over this 128-chunk of h[b0+4r+i][k] * W_row(g*256 + h0 + c)[k]
__device__ __forceinline__ void gemm32(float acc[4][4], const float4* As, const float4* Bs,
                                       int r, int c) {
  const int sa = r & 7;
  const int sb = c & 7;  // (c+16g)&7 == c&7
#pragma unroll 4
  for (int kq = 0; kq < 32; ++kq) {
    float4 a[4], b[4];
#pragma unroll
    for (int i = 0; i < 4; ++i) a[i] = As[(4 * r + i) * 32 + (kq ^ sa)];
#pragma unroll
    for (int g = 0; g < 4; ++g) b[g] = Bs[(c + 16 * g) * 32 + (kq ^ sb)];
#pragma unroll
    for (int i = 0; i < 4; ++i)
#pragma unroll
      for (int g = 0; g < 4; ++g)
        acc[i][g] += a[i].x * b[g].x + a[i].y * b[g].y + a[i].z * b[g].z + a[i].w * b[g].w;
  }
}

__device__ __forceinline__ void gemm_full(float (&acc)[4][4], const float* __restrict__ h,
                                          const float* __restrict__ W, int b0, int h0,
                                          int tx, int r, int c, float4* As, float4* Bs) {
#pragma unroll
  for (int kc = 0; kc < 2; ++kc) {
    stage_h_chunk(As, h, b0, kc, tx);
    stage_w_chunk(Bs, W, h0, kc, tx);
    __syncthreads();
    gemm32(acc, As, Bs, r, c);
    __syncthreads();
  }
}

// ---------------- layer-0 step (scalar input) ----------------
// input pv = (xcol>=0) ? xsrc[b*NLOOK+xcol] : predin[b]
// Optionally zeroes predzero[0..NB) and flushes predin to out column outcol.
__global__ __launch_bounds__(TPB) void l0_step(
    const float* __restrict__ xsrc, int xcol,
    const float* __restrict__ predin, float* __restrict__ predzero,
    float* __restrict__ outw, int outcol,
    const float* __restrict__ Wih, const float* __restrict__ Whh,
    const float* __restrict__ bias,
    const float* __restrict__ hprev, float* __restrict__ hout,
    float4* __restrict__ cst, int first) {
  __shared__ float4 As[2048];
  __shared__ float4 Bs[2048];
  const int tx = threadIdx.x, bx = blockIdx.x;
  const int b0 = (bx >> 4) * 64, h0 = (bx & 15) * 16;
  const int r = tx & 15, c = tx >> 4, hg = h0 + c;

  if (predzero != nullptr && tx < 4) predzero[bx * 4 + tx] = 0.0f;
  if (outw != nullptr && tx < 4) {
    const int b = bx * 4 + tx;
    outw[b * NHOR + outcol] = predin[b];
  }

  float acc[4][4] = {};
  if (!first) gemm_full(acc, hprev, Whh, b0, h0, tx, r, c, As, Bs);

  float wv[4], bv[4];
#pragma unroll
  for (int g = 0; g < 4; ++g) { wv[g] = Wih[g * NH + hg]; bv[g] = bias[g * NH + hg]; }

  float cold[4] = {0.f, 0.f, 0.f, 0.f};
  if (!first) {
    const float4 cv = cst[bx * TPB + tx];
    cold[0] = cv.x; cold[1] = cv.y; cold[2] = cv.z; cold[3] = cv.w;
  }
  float cnew[4];
#pragma unroll
  for (int i = 0; i < 4; ++i) {
    const int b = b0 + 4 * r + i;
    const float pv = (xcol >= 0) ? xsrc[b * NLOOK + xcol] : predin[b];
    const float ig = sigm(acc[i][0] + pv * wv[0] + bv[0]);
    const float fg = sigm(acc[i][1] + pv * wv[1] + bv[1]);
    const float gg = tanhf(acc[i][2] + pv * wv[2] + bv[2]);
    const float og = sigm(acc[i][3] + pv * wv[3] + bv[3]);
    cnew[i] = fg * cold[i] + ig * gg;
    hout[b * NH + hg] = og * tanhf(cnew[i]);
  }
  cst[bx * TPB + tx] = make_float4(cnew[0], cnew[1], cnew[2], cnew[3]);
}

// ---------------- layer-1 step (vector input) ----------------
// gates = hin @ Wih^T + (first ? 0 : hprev @ Whh^T) + bias ; optional fc into predacc.
__global__ __launch_bounds__(TPB) void l1_step(
    const float* __restrict__ hin, const float* __restrict__ hprev,
    const float* __restrict__ Wih, const float* __restrict__ Whh,
    const float* __restrict__ bias,
    float* __restrict__ hout, float4* __restrict__ cst, int first,
    const float* __restrict__ fcW, const float* __restrict__ fcb,
    float* __restrict__ predacc) {
  __shared__ float4 As[2048];
  __shared__ float4 Bs[2048];
  const int tx = threadIdx.x, bx = blockIdx.x;
  const int b0 = (bx >> 4) * 64, h0 = (bx & 15) * 16;
  const int r = tx & 15, c = tx >> 4, hg = h0 + c;

  float acc[4][4] = {};
  gemm_full(acc, hin, Wih, b0, h0, tx, r, c, As, Bs);
  if (!first) gemm_full(acc, hprev, Whh, b0, h0, tx, r, c, As, Bs);

  float bv[4];
#pragma unroll
  for (int g = 0; g < 4; ++g) bv[g] = bias[g * NH + hg];

  float cold[4] = {0.f, 0.f, 0.f, 0.f};
  if (!first) {
    const float4 cv = cst[bx * TPB + tx];
    cold[0] = cv.x; cold[1] = cv.y; cold[2] = cv.z; cold[3] = cv.w;
  }
  float cnew[4], hv[4];
#pragma unroll
  for (int i = 0; i < 4; ++i) {
    const int b = b0 + 4 * r + i;
    const float ig = sigm(acc[i][0] + bv[0]);
    const float fg = sigm(acc[i][1] + bv[1]);
    const float gg = tanhf(acc[i][2] + bv[2]);
    const float og = sigm(acc[i][3] + bv[3]);
    cnew[i] = fg * cold[i] + ig * gg;
    hv[i] = og * tanhf(cnew[i]);
    hout[b * NH + hg] = hv[i];
  }
  cst[bx * TPB + tx] = make_float4(cnew[0], cnew[1], cnew[2], cnew[3]);

  if (predacc != nullptr) {
    // gemm_full ended with __syncthreads(): As is reusable now.
    const float fcw = fcW[hg];
    float* red = (float*)As;  // 64 x 16
#pragma unroll
    for (int i = 0; i < 4; ++i) red[(4 * r + i) * 16 + c] = hv[i] * fcw;
    __syncthreads();
    if (tx < 64) {
      float s = 0.0f;
#pragma unroll
      for (int q = 0; q < 16; ++q) s += red[tx * 16 + q];
      if ((bx & 15) == 0) s += fcb[0];
      atomicAdd(&predacc[b0 + tx], s);
    }
  }
}

__global__ __launch_bounds__(TPB) void finalize(float* __restrict__ out,
                                                const float* __restrict__ pred) {
  const int b = blockIdx.x * blockDim.x + threadIdx.x;
  if (b < NB) out[b * NHOR + (NHOR - 1)] = pred[b];
}

extern "C" void kernel_launch(void* const* d_in, const int* in_sizes, int n_in,
                              void* d_out, int out_size, void* d_ws, size_t ws_size,
                              hipStream_t stream) {
  (void)in_sizes; (void)n_in; (void)out_size; (void)ws_size;
  const float* x     = (const float*)d_in[0];
  const float* eWih0 = (const float*)d_in[1];
  const float* eWhh0 = (const float*)d_in[2];
  const float* eb0   = (const float*)d_in[3];
  const float* eWih1 = (const float*)d_in[4];
  const float* eWhh1 = (const float*)d_in[5];
  const float* eb1   = (const float*)d_in[6];
  const float* dWih0 = (const float*)d_in[7];
  const float* dWhh0 = (const float*)d_in[8];
  const float* db0   = (const float*)d_in[9];
  const float* dWih1 = (const float*)d_in[10];
  const float* dWhh1 = (const float*)d_in[11];
  const float* db1   = (const float*)d_in[12];
  const float* fcW   = (const float*)d_in[13];
  const float* fcb   = (const float*)d_in[14];
  float* out = (float*)d_out;
  float* ws  = (float*)d_ws;

  const size_t HB = (size_t)NB * NH;  // 262144 floats
  float* h0a = ws;
  float* h0b = ws + HB;
  float* h1a = ws + 2 * HB;
  float* h1b = ws + 3 * HB;
  float4* c0 = (float4*)(ws + 4 * HB);
  float4* c1 = (float4*)(ws + 5 * HB);
  float* pra = ws + 6 * HB;
  float* prb = pra + NB;

  dim3 grid(256), block(TPB);

  float* h0c = h0a; float* h0n = h0b;
  float* h1c = h1a; float* h1n = h1b;

  // ---------------- encoder ----------------
  for (int t = 0; t < NLOOK; ++t) {
    l0_step<<<grid, block, 0, stream>>>(x, t, nullptr, nullptr, nullptr, 0,
                                        eWih0, eWhh0, eb0, h0c, h0n, c0, t == 0);
    l1_step<<<grid, block, 0, stream>>>(h0n, h1c, eWih1, eWhh1, eb1,
                                        h1n, c1, t == 0, nullptr, nullptr, nullptr);
    { float* tmp = h0c; h0c = h0n; h0n = tmp; }
    { float* tmp = h1c; h1c = h1n; h1n = tmp; }
  }

  // ---------------- decoder ----------------
  float* pr[2] = { pra, prb };
  for (int t = 0; t < NHOR; ++t) {
    float* accb = pr[t & 1];
    float* inb  = pr[(t & 1) ^ 1];
    const int xcol = (t == 0) ? (NLOOK - 1) : -1;
    l0_step<<<grid, block, 0, stream>>>(x, xcol,
                                        (t == 0) ? nullptr : inb, accb,
                                        (t == 0) ? nullptr : out, t - 1,
                                        dWih0, dWhh0, db0, h0c, h0n, c0, 0);
    l1_step<<<grid, block, 0, stream>>>(h0n, h1c, dWih1, dWhh1, db1,
                                        h1n, c1, 0, fcW, fcb, accb);
    { float* tmp = h0c; h0c = h0n; h0n = tmp; }
    { float* tmp = h1c; h1c = h1n; h1n = tmp; }
  }

  // last column (NHOR-1 is odd -> pr[1])
  finalize<<<dim3(4), block, 0, stream>>>(out, pr[(NHOR - 1) & 1]);
}

// Round 4
// 19675.726 us; speedup vs baseline: 1.2691x; 1.2691x over previous
//
#include <hip/hip_runtime.h>
#include <stdint.h>
#include <math.h>

#define NB 1024      // batch
#define NH 256       // hidden
#define NG 1024      // 4*NH gate rows
#define NLOOK 336    // encoder steps
#define NHOR 168     // decoder steps
#define TPB 256

// ---------- bf16 helpers (RNE) ----------
__device__ __forceinline__ unsigned short bf16_rne(float f) {
  union { float f; uint32_t u; } v; v.f = f;
  uint32_t u = v.u;
  u += 0x7FFFu + ((u >> 16) & 1u);
  return (unsigned short)(u >> 16);
}
__device__ __forceinline__ float bf16_f(unsigned short h) {
  union { uint32_t u; float f; } v; v.u = ((uint32_t)h) << 16;
  return v.f;
}
__device__ __forceinline__ float sigm(float x) { return 1.0f / (1.0f + expf(-x)); }

typedef short bf16x8 __attribute__((ext_vector_type(8)));
typedef float f32x4 __attribute__((ext_vector_type(4)));

// ---------- weight split prologue: W(fp32) -> hi/lo bf16 planes ----------
__global__ __launch_bounds__(TPB) void split_w(const float* __restrict__ W,
                                               unsigned short* __restrict__ hi,
                                               unsigned short* __restrict__ lo) {
  const int idx = blockIdx.x * TPB + threadIdx.x;
  const float w = W[idx];
  const unsigned short h = bf16_rne(w);
  hi[idx] = h;
  lo[idx] = bf16_rne(w - bf16_f(h));
}

// ---------- split-bf16 MFMA GEMM: acc[g] += h[64xK] @ W[gate rows]^T ----------
// Block tile: 64 batch rows (b0..b0+63) x 64 gate cols (4 gates x 16 hcols at h0off).
// wave wv = m-tile (16 rows); lane: lg=l>>4 (k-group), ln16=l&15.
// A-frag: lane holds h[b0+wv*16+ln16][kt*32+lg*8 .. +7]  (16B contiguous)
// B-frag: lane holds W[g*256+h0off+ln16][kt*32+lg*8 .. +7] (16B contiguous)
// D: lane reg r -> row b0+wv*16+lg*4+r, col h0off+ln16.
__device__ __forceinline__ void gemm_acc(f32x4 acc[4],
                                         const unsigned short* __restrict__ hhi,
                                         const unsigned short* __restrict__ hlo,
                                         const unsigned short* __restrict__ whi,
                                         const unsigned short* __restrict__ wlo,
                                         int b0, int h0off, int wv, int lg, int ln16) {
  const int arow = b0 + wv * 16 + ln16;
  const unsigned short* ah = hhi + arow * NH;
  const unsigned short* al = hlo + arow * NH;
  const unsigned short* bh0 = whi + (h0off + ln16) * NH;
  const unsigned short* bl0 = wlo + (h0off + ln16) * NH;
#pragma unroll
  for (int kt = 0; kt < 8; ++kt) {
    const int ko = kt * 32 + lg * 8;
    const bf16x8 Ah = *(const bf16x8*)(ah + ko);
    const bf16x8 Al = *(const bf16x8*)(al + ko);
#pragma unroll
    for (int g = 0; g < 4; ++g) {
      const bf16x8 Bh = *(const bf16x8*)(bh0 + g * (NH * NH) + ko);
      const bf16x8 Bl = *(const bf16x8*)(bl0 + g * (NH * NH) + ko);
      acc[g] = __builtin_amdgcn_mfma_f32_16x16x32_bf16(Ah, Bh, acc[g], 0, 0, 0);
      acc[g] = __builtin_amdgcn_mfma_f32_16x16x32_bf16(Ah, Bl, acc[g], 0, 0, 0);
      acc[g] = __builtin_amdgcn_mfma_f32_16x16x32_bf16(Al, Bh, acc[g], 0, 0, 0);
    }
  }
}

// ---------------- layer-0 step (scalar input) ----------------
__global__ __launch_bounds__(TPB, 1) void l0_step(
    const float* __restrict__ xsrc, int xcol,
    const float* __restrict__ predin, float* __restrict__ predzero,
    float* __restrict__ outw, int outcol,
    const float* __restrict__ Wih, const float* __restrict__ bias,
    const unsigned short* __restrict__ whh_hi, const unsigned short* __restrict__ whh_lo,
    const unsigned short* __restrict__ hprev_hi, const unsigned short* __restrict__ hprev_lo,
    unsigned short* __restrict__ hout_hi, unsigned short* __restrict__ hout_lo,
    float* __restrict__ cbuf, int first) {
  const int tx = threadIdx.x, bx = blockIdx.x;
  const int b0 = (bx >> 4) * 64, h0off = (bx & 15) * 16;
  const int wv = tx >> 6, l = tx & 63, lg = l >> 4, ln16 = l & 15;

  if (predzero != nullptr && tx < 4) predzero[bx * 4 + tx] = 0.0f;
  if (outw != nullptr && tx < 4) {
    const int b = bx * 4 + tx;
    outw[b * NHOR + outcol] = predin[b];
  }

  f32x4 acc[4] = {};
  if (!first) gemm_acc(acc, hprev_hi, hprev_lo, whh_hi, whh_lo, b0, h0off, wv, lg, ln16);

  const int hcol = h0off + ln16;
  float wv4[4], bv4[4];
#pragma unroll
  for (int g = 0; g < 4; ++g) {
    wv4[g] = Wih[g * NH + hcol];
    bv4[g] = bias[g * NH + hcol];
  }

#pragma unroll
  for (int r = 0; r < 4; ++r) {
    const int b = b0 + wv * 16 + lg * 4 + r;
    const float pv = (xcol >= 0) ? xsrc[b * NLOOK + xcol] : predin[b];
    const float ig = sigm(acc[0][r] + pv * wv4[0] + bv4[0]);
    const float fg = sigm(acc[1][r] + pv * wv4[1] + bv4[1]);
    const float gg = tanhf(acc[2][r] + pv * wv4[2] + bv4[2]);
    const float og = sigm(acc[3][r] + pv * wv4[3] + bv4[3]);
    const float cold = first ? 0.0f : cbuf[b * NH + hcol];
    const float cnew = fg * cold + ig * gg;
    cbuf[b * NH + hcol] = cnew;
    const float hv = og * tanhf(cnew);
    const unsigned short hb = bf16_rne(hv);
    hout_hi[b * NH + hcol] = hb;
    hout_lo[b * NH + hcol] = bf16_rne(hv - bf16_f(hb));
  }
}

// ---------------- layer-1 step (vector input) + optional fc ----------------
__global__ __launch_bounds__(TPB, 1) void l1_step(
    const unsigned short* __restrict__ hin_hi, const unsigned short* __restrict__ hin_lo,
    const unsigned short* __restrict__ hprev_hi, const unsigned short* __restrict__ hprev_lo,
    const unsigned short* __restrict__ wih_hi, const unsigned short* __restrict__ wih_lo,
    const unsigned short* __restrict__ whh_hi, const unsigned short* __restrict__ whh_lo,
    const float* __restrict__ bias,
    unsigned short* __restrict__ hout_hi, unsigned short* __restrict__ hout_lo,
    float* __restrict__ cbuf, int first,
    const float* __restrict__ fcW, const float* __restrict__ fcb,
    float* __restrict__ predacc) {
  const int tx = threadIdx.x, bx = blockIdx.x;
  const int b0 = (bx >> 4) * 64, h0off = (bx & 15) * 16;
  const int wv = tx >> 6, l = tx & 63, lg = l >> 4, ln16 = l & 15;

  f32x4 acc[4] = {};
  gemm_acc(acc, hin_hi, hin_lo, wih_hi, wih_lo, b0, h0off, wv, lg, ln16);
  if (!first) gemm_acc(acc, hprev_hi, hprev_lo, whh_hi, whh_lo, b0, h0off, wv, lg, ln16);

  const int hcol = h0off + ln16;
  float bv4[4];
#pragma unroll
  for (int g = 0; g < 4; ++g) bv4[g] = bias[g * NH + hcol];

  float hvr[4];
#pragma unroll
  for (int r = 0; r < 4; ++r) {
    const int b = b0 + wv * 16 + lg * 4 + r;
    const float ig = sigm(acc[0][r] + bv4[0]);
    const float fg = sigm(acc[1][r] + bv4[1]);
    const float gg = tanhf(acc[2][r] + bv4[2]);
    const float og = sigm(acc[3][r] + bv4[3]);
    const float cold = first ? 0.0f : cbuf[b * NH + hcol];
    const float cnew = fg * cold + ig * gg;
    cbuf[b * NH + hcol] = cnew;
    const float hv = og * tanhf(cnew);
    hvr[r] = hv;
    const unsigned short hb = bf16_rne(hv);
    hout_hi[b * NH + hcol] = hb;
    hout_lo[b * NH + hcol] = bf16_rne(hv - bf16_f(hb));
  }

  if (predacc != nullptr) {
    const float fcwv = fcW[hcol];
    float s[4];
#pragma unroll
    for (int r = 0; r < 4; ++r) s[r] = hvr[r] * fcwv;
#pragma unroll
    for (int m = 1; m < 16; m <<= 1) {
#pragma unroll
      for (int r = 0; r < 4; ++r) s[r] += __shfl_xor(s[r], m, 64);
    }
    if (ln16 == 0) {
#pragma unroll
      for (int r = 0; r < 4; ++r) {
        const int b = b0 + wv * 16 + lg * 4 + r;
        float v = s[r];
        if ((bx & 15) == 0) v += fcb[0];
        atomicAdd(&predacc[b], v);
      }
    }
  }
}

__global__ __launch_bounds__(TPB) void finalize(float* __restrict__ out,
                                                const float* __restrict__ pred) {
  const int b = blockIdx.x * blockDim.x + threadIdx.x;
  if (b < NB) out[b * NHOR + (NHOR - 1)] = pred[b];
}

extern "C" void kernel_launch(void* const* d_in, const int* in_sizes, int n_in,
                              void* d_out, int out_size, void* d_ws, size_t ws_size,
                              hipStream_t stream) {
  (void)in_sizes; (void)n_in; (void)out_size; (void)ws_size;
  const float* x     = (const float*)d_in[0];
  const float* eWih0 = (const float*)d_in[1];
  const float* eWhh0 = (const float*)d_in[2];
  const float* eb0   = (const float*)d_in[3];
  const float* eWih1 = (const float*)d_in[4];
  const float* eWhh1 = (const float*)d_in[5];
  const float* eb1   = (const float*)d_in[6];
  const float* dWih0 = (const float*)d_in[7];
  const float* dWhh0 = (const float*)d_in[8];
  const float* db0   = (const float*)d_in[9];
  const float* dWih1 = (const float*)d_in[10];
  const float* dWhh1 = (const float*)d_in[11];
  const float* db1   = (const float*)d_in[12];
  const float* fcW   = (const float*)d_in[13];
  const float* fcb   = (const float*)d_in[14];
  float* out = (float*)d_out;

  const size_t P = (size_t)NG * NH;  // 262144 elems per plane
  unsigned short* wsu = (unsigned short*)d_ws;
  // 6 split weight matrices: [m*2P .. ) hi, lo
  unsigned short* Whi[6]; unsigned short* Wlo[6];
  const float* Wsrc[6] = { eWhh0, eWih1, eWhh1, dWhh0, dWih1, dWhh1 };
  for (int m = 0; m < 6; ++m) { Whi[m] = wsu + (size_t)m * 2 * P; Wlo[m] = wsu + (size_t)m * 2 * P + P; }
  // h planes: 8 planes of P ushorts after 12P
  unsigned short* hp = wsu + 12 * P;
  unsigned short* h0a_hi = hp + 0 * P; unsigned short* h0a_lo = hp + 1 * P;
  unsigned short* h0b_hi = hp + 2 * P; unsigned short* h0b_lo = hp + 3 * P;
  unsigned short* h1a_hi = hp + 4 * P; unsigned short* h1a_lo = hp + 5 * P;
  unsigned short* h1b_hi = hp + 6 * P; unsigned short* h1b_lo = hp + 7 * P;
  // c buffers (f32) after 20P ushorts
  float* cf = (float*)(wsu + 20 * P);
  float* c0buf = cf;
  float* c1buf = cf + P;
  float* pra = cf + 2 * P;
  float* prb = pra + NB;

  dim3 grid(256), block(TPB);

  // prologue: split weights (deterministic, every call)
  for (int m = 0; m < 6; ++m)
    split_w<<<dim3(P / TPB), block, 0, stream>>>(Wsrc[m], Whi[m], Wlo[m]);

  unsigned short* h0c_hi = h0a_hi; unsigned short* h0c_lo = h0a_lo;
  unsigned short* h0n_hi = h0b_hi; unsigned short* h0n_lo = h0b_lo;
  unsigned short* h1c_hi = h1a_hi; unsigned short* h1c_lo = h1a_lo;
  unsigned short* h1n_hi = h1b_hi; unsigned short* h1n_lo = h1b_lo;

  // ---------------- encoder ----------------
  for (int t = 0; t < NLOOK; ++t) {
    l0_step<<<grid, block, 0, stream>>>(x, t, nullptr, nullptr, nullptr, 0,
                                        eWih0, eb0, Whi[0], Wlo[0],
                                        h0c_hi, h0c_lo, h0n_hi, h0n_lo, c0buf, t == 0);
    l1_step<<<grid, block, 0, stream>>>(h0n_hi, h0n_lo, h1c_hi, h1c_lo,
                                        Whi[1], Wlo[1], Whi[2], Wlo[2], eb1,
                                        h1n_hi, h1n_lo, c1buf, t == 0,
                                        nullptr, nullptr, nullptr);
    { unsigned short* t1 = h0c_hi; h0c_hi = h0n_hi; h0n_hi = t1; }
    { unsigned short* t1 = h0c_lo; h0c_lo = h0n_lo; h0n_lo = t1; }
    { unsigned short* t1 = h1c_hi; h1c_hi = h1n_hi; h1n_hi = t1; }
    { unsigned short* t1 = h1c_lo; h1c_lo = h1n_lo; h1n_lo = t1; }
  }

  // ---------------- decoder ----------------
  float* pr[2] = { pra, prb };
  for (int t = 0; t < NHOR; ++t) {
    float* accb = pr[t & 1];
    float* inb  = pr[(t & 1) ^ 1];
    const int xcol = (t == 0) ? (NLOOK - 1) : -1;
    l0_step<<<grid, block, 0, stream>>>(x, xcol,
                                        (t == 0) ? nullptr : inb, accb,
                                        (t == 0) ? nullptr : out, t - 1,
                                        dWih0, db0, Whi[3], Wlo[3],
                                        h0c_hi, h0c_lo, h0n_hi, h0n_lo, c0buf, 0);
    l1_step<<<grid, block, 0, stream>>>(h0n_hi, h0n_lo, h1c_hi, h1c_lo,
                                        Whi[4], Wlo[4], Whi[5], Wlo[5], db1,
                                        h1n_hi, h1n_lo, c1buf, 0,
                                        fcW, fcb, accb);
    { unsigned short* t1 = h0c_hi; h0c_hi = h0n_hi; h0n_hi = t1; }
    { unsigned short* t1 = h0c_lo; h0c_lo = h0n_lo; h0n_lo = t1; }
    { unsigned short* t1 = h1c_hi; h1c_hi = h1n_hi; h1n_hi = t1; }
    { unsigned short* t1 = h1c_lo; h1c_lo = h1n_lo; h1n_lo = t1; }
  }

  finalize<<<dim3(4), block, 0, stream>>>(out, pr[(NHOR - 1) & 1]);
}